// Round 4
// baseline (248.510 us; speedup 1.0000x reference)
//
#include <hip/hip_runtime.h>
#include <hip/hip_bf16.h>
#include <cstddef>
#include <cstdint>

// (B, L, D, H) = (2, 2048, 1024, 16), KD = 64.
#define L_SEQ   2048
#define D_MODEL 1024
#define NH      16
#define HKD     64
#define TD3     3072
#define NBATCH  2

typedef __attribute__((ext_vector_type(8))) short bf16x8;
typedef __attribute__((ext_vector_type(4))) float f32x4;

__device__ __forceinline__ unsigned short f2bf(float f) {
  unsigned int u = __float_as_uint(f);
  u += 0x7fffu + ((u >> 16) & 1u);   // round-to-nearest-even
  return (unsigned short)(u >> 16);
}

__device__ __forceinline__ unsigned int pk2bf(float a, float b) {
  union { __hip_bfloat162 h; unsigned int u; } cv;
  cv.h = __float22bfloat162_rn(make_float2(a, b));
  return cv.u;
}

__device__ __forceinline__ void gll16(const void* g, void* l) {
  __builtin_amdgcn_global_load_lds(
      (const __attribute__((address_space(1))) unsigned int*)g,
      (__attribute__((address_space(3))) unsigned int*)l, 16, 0, 0);
}

// ---------------------------------------------------------------------------
// fp32 -> bf16, 8 elems/thread
// ---------------------------------------------------------------------------
__global__ __launch_bounds__(256)
void cvt_f32_bf16(const float* __restrict__ in, unsigned short* __restrict__ out) {
  const int i = blockIdx.x * 256 + threadIdx.x;
  const float4 a = ((const float4*)in)[2 * i];
  const float4 b = ((const float4*)in)[2 * i + 1];
  bf16x8 v;
  v[0] = (short)f2bf(a.x); v[1] = (short)f2bf(a.y);
  v[2] = (short)f2bf(a.z); v[3] = (short)f2bf(a.w);
  v[4] = (short)f2bf(b.x); v[5] = (short)f2bf(b.y);
  v[6] = (short)f2bf(b.z); v[7] = (short)f2bf(b.w);
  ((bf16x8*)out)[i] = v;
}

// ---------------------------------------------------------------------------
// W[K][N] fp32 -> WT[N][K] bf16 (64x64 tiles through LDS)
// ---------------------------------------------------------------------------
__global__ __launch_bounds__(256)
void transpose_cvt(const float* __restrict__ W, unsigned short* __restrict__ WT,
                   int K, int N) {
  __shared__ unsigned short T[64][68];
  const int t = threadIdx.x;
  const int n0 = blockIdx.x * 64, k0 = blockIdx.y * 64;
  const int cr = t >> 4, cc = (t & 15) * 4;
#pragma unroll
  for (int i = 0; i < 4; ++i) {
    const int k = cr + 16 * i;
    const float4 v = *(const float4*)(W + (size_t)(k0 + k) * N + n0 + cc);
    T[cc + 0][k] = f2bf(v.x); T[cc + 1][k] = f2bf(v.y);
    T[cc + 2][k] = f2bf(v.z); T[cc + 3][k] = f2bf(v.w);
  }
  __syncthreads();
#pragma unroll
  for (int i = 0; i < 4; ++i) {
    const int n = cr + 16 * i;
    ushort4 o;
    o.x = T[n][cc]; o.y = T[n][cc + 1]; o.z = T[n][cc + 2]; o.w = T[n][cc + 3];
    *(ushort4*)(WT + (size_t)(n0 + n) * K + k0 + cc) = o;
  }
}

// ---------------------------------------------------------------------------
// bf16 MFMA GEMM, m97-style: C[M,N] = A[M,K] * Bt[N,K]^T.
// 128x128 tile, BK=64, 256 threads (4 waves, 2x2), 4x4 16x16x32 frags/wave.
// XCD-aware bijective block swizzle (grid multiple of 8).
// ---------------------------------------------------------------------------
template <typename OUT>
__device__ __forceinline__ OUT cvt_out(float f);
template <> __device__ __forceinline__ float cvt_out<float>(float f) { return f; }
template <> __device__ __forceinline__ unsigned short cvt_out<unsigned short>(float f) { return f2bf(f); }

template <typename OUT>
__global__ __launch_bounds__(256)
void gemm_bf16(const unsigned short* __restrict__ A,   // [M][K] bf16
               const unsigned short* __restrict__ Bt,  // [N][K] bf16
               OUT* __restrict__ C, int M, int N, int K) {
  __shared__ unsigned short As[128 * 64];
  __shared__ unsigned short Bs[128 * 64];
  const int t = threadIdx.x, w = t >> 6, lane = t & 63;
  const int lg = lane >> 4, lq = lane & 15;

  // XCD swizzle: contiguous chunk of blocks per XCD (nwg % 8 == 0)
  const int nwg = gridDim.x * gridDim.y;
  int bid = blockIdx.y * gridDim.x + blockIdx.x;
  bid = (bid & 7) * (nwg >> 3) + (bid >> 3);
  const int m0 = (bid / gridDim.x) * 128, n0 = (bid % gridDim.x) * 128;
  const int wr = w >> 1, wc = w & 1;

  f32x4 acc[4][4];
#pragma unroll
  for (int a = 0; a < 4; ++a)
#pragma unroll
    for (int b = 0; b < 4; ++b) acc[a][b] = (f32x4)0.f;

  for (int k0 = 0; k0 < K; k0 += 64) {
    __syncthreads();  // previous iteration's LDS reads done
#pragma unroll
    for (int i = 0; i < 4; ++i) {
      const int c = 256 * i + t;            // chunk 0..1023 (16B each)
      const int row = c >> 3, cc = (c & 7) * 8;
      gll16(A + (size_t)(m0 + row) * K + k0 + cc,
            (char*)As + (256 * i + 64 * w) * 16);
      gll16(Bt + (size_t)(n0 + row) * K + k0 + cc,
            (char*)Bs + (256 * i + 64 * w) * 16);
    }
    __syncthreads();  // drains vmcnt -> tiles ready
#pragma unroll
    for (int ks = 0; ks < 2; ++ks) {
      bf16x8 af[4], bfr[4];
#pragma unroll
      for (int mf = 0; mf < 4; ++mf)
        af[mf] = *(const bf16x8*)((const char*)As +
                   (wr * 64 + mf * 16 + lq) * 128 + ks * 64 + lg * 16);
#pragma unroll
      for (int nf = 0; nf < 4; ++nf)
        bfr[nf] = *(const bf16x8*)((const char*)Bs +
                   (wc * 64 + nf * 16 + lq) * 128 + ks * 64 + lg * 16);
#pragma unroll
      for (int mf = 0; mf < 4; ++mf)
#pragma unroll
        for (int nf = 0; nf < 4; ++nf)
          acc[mf][nf] = __builtin_amdgcn_mfma_f32_16x16x32_bf16(
              af[mf], bfr[nf], acc[mf][nf], 0, 0, 0);
    }
  }

  // C/D layout: col = lane&15, row = (lane>>4)*4 + reg  [m89]
#pragma unroll
  for (int mf = 0; mf < 4; ++mf)
#pragma unroll
    for (int nf = 0; nf < 4; ++nf) {
      const int col = n0 + wc * 64 + nf * 16 + lq;
#pragma unroll
      for (int r = 0; r < 4; ++r) {
        const int row = m0 + wr * 64 + mf * 16 + lg * 4 + r;
        C[(size_t)row * N + col] = cvt_out<OUT>(acc[mf][nf][r]);
      }
    }
}

// ---------------------------------------------------------------------------
// Reference's direct reshape: head h, attn row s <-> memory row h*128 + s/16,
// cols (s%16)*64 (+ part*D_MODEL).
// ---------------------------------------------------------------------------
__device__ __forceinline__ size_t head_row(int part, int b, int h, int s) {
  return ((size_t)(b * L_SEQ + h * 128 + (s >> 4))) * TD3 +
         (size_t)part * D_MODEL + (size_t)(s & 15) * HKD;
}

// ---------------------------------------------------------------------------
// V pre-transpose: vT[b][h][d][s]
// ---------------------------------------------------------------------------
__global__ __launch_bounds__(256)
void transpose_v(const unsigned short* __restrict__ qkv,
                 unsigned short* __restrict__ vT) {
  __shared__ unsigned short T[64][68];
  const int t = threadIdx.x;
  const int kt = blockIdx.x, bh = blockIdx.y, b = bh >> 4, h = bh & 15;
  const int s0 = kt * 64;
  const int sr = t >> 4, c4 = (t & 15) * 4;
#pragma unroll
  for (int i = 0; i < 4; ++i) {
    const int s = sr + 16 * i;
    const ushort4 v = *(const ushort4*)(qkv + head_row(2, b, h, s0 + s) + c4);
    T[c4 + 0][s] = v.x; T[c4 + 1][s] = v.y;
    T[c4 + 2][s] = v.z; T[c4 + 3][s] = v.w;
  }
  __syncthreads();
#pragma unroll
  for (int i = 0; i < 4; ++i) {
    const int d = sr + 16 * i;
    ushort4 o;
    o.x = T[d][c4]; o.y = T[d][c4 + 1]; o.z = T[d][c4 + 2]; o.w = T[d][c4 + 3];
    *(ushort4*)(vT + ((size_t)(bh * 64 + d)) * L_SEQ + s0 + c4) = o;
  }
}

// ---------------------------------------------------------------------------
// MFMA flash attention. QBLK=64 (4 waves), KVBLK=64, heavy-first launch,
// double-buffered K/V^T via global_load_lds. Swapped operands:
// S^T = mfma(K, Q^T), O^T = mfma(V^T, P^T). Softmax in log2 domain
// (scale folded into Q), diagonal-only masking, defer-max (THR=8),
// cvt_pk P-packing.
// ---------------------------------------------------------------------------
#define QK_SCALE 0.18033688011112043f   // log2(e)/8

__global__ __launch_bounds__(256)
void attn_mfma(const unsigned short* __restrict__ qkv,
               const unsigned short* __restrict__ vT,
               unsigned short* __restrict__ concat) {
  __shared__ unsigned short Ks[2][64 * 64];  // [key][d], chunk-XOR swizzled
  __shared__ unsigned short Vs[2][64 * 64];  // [d][key], chunk-XOR swizzled
  __shared__ unsigned short Pl[4][16][72];   // per-wave P[q][key], padded

  const int t = threadIdx.x, w = t >> 6, lane = t & 63;
  const int lg = lane >> 4, lq = lane & 15;
  const int qt = 31 - blockIdx.x;            // heavy blocks first
  const int bh = blockIdx.y, b = bh >> 4, h = bh & 15;
  const int q0 = qt * 64;
  const int qrow = q0 + w * 16 + lq;         // this lane's q row

  // Q fragments, pre-scaled by log2(e)/sqrt(KD) (softmax in log2 domain)
  bf16x8 qf[2];
  {
    const size_t qb = head_row(0, b, h, qrow) + lg * 8;
    qf[0] = *(const bf16x8*)(qkv + qb);
    qf[1] = *(const bf16x8*)(qkv + qb + 32);
#pragma unroll
    for (int s = 0; s < 2; ++s)
#pragma unroll
      for (int j = 0; j < 8; ++j) {
        const float f =
            __uint_as_float(((unsigned int)(unsigned short)qf[s][j]) << 16);
        qf[s][j] = (short)f2bf(f * QK_SCALE);
      }
  }

  // staging: thread t stages chunks c = 256*i + t (i=0,1) of each 64x64 tile.
  // dest linear; source column XOR-swizzled (involution; reads apply same).
  const int srow = t >> 3;                   // 0..31
  const int swz = ((t & 7) ^ (srow & 7)) * 8;
  size_t kSrc[2], vSrc[2];
#pragma unroll
  for (int i = 0; i < 2; ++i) {
    const int skey = 32 * i + srow;
    kSrc[i] = head_row(1, b, h, skey) + swz;              // += k0*192 per tile
    vSrc[i] = ((size_t)(bh * 64 + skey)) * L_SEQ + swz;   // += k0 per tile
  }
  char* const kDst = (char*)&Ks[0][0] + w * 1024;
  char* const vDst = (char*)&Vs[0][0] + w * 1024;

  f32x4 o[4];
#pragma unroll
  for (int mf = 0; mf < 4; ++mf) o[mf] = (f32x4)0.f;
  float mrun = -1e30f, lrun = 0.f;

  // prologue: stage tile 0 into buffer 0
#pragma unroll
  for (int i = 0; i < 2; ++i) {
    gll16(qkv + kSrc[i], kDst + i * 4096);
    gll16(vT + vSrc[i], vDst + i * 4096);
  }

  for (int kt = 0; kt <= qt; ++kt) {
    const int k0 = kt * 64;
    const int cur = kt & 1;
    __syncthreads();  // vmcnt drained: buf[cur] ready; buf[1-cur] reads done

    if (kt < qt) {  // issue next tile into the other buffer (overlaps compute)
      const int nb = (1 - cur) * 8192;
#pragma unroll
      for (int i = 0; i < 2; ++i) {
        gll16(qkv + kSrc[i] + (size_t)(k0 + 64) * 192, kDst + nb + i * 4096);
        gll16(vT + vSrc[i] + (size_t)(k0 + 64), vDst + nb + i * 4096);
      }
    }
    const char* kb = (const char*)&Ks[cur][0];
    const char* vb = (const char*)&Vs[cur][0];

    // S^T = K * Q^T : lane holds S^T[key=16mf+4lg+r][q=lq] (log2-scaled)
    f32x4 s[4];
#pragma unroll
    for (int mf = 0; mf < 4; ++mf) s[mf] = (f32x4)0.f;
    __builtin_amdgcn_s_setprio(1);
#pragma unroll
    for (int ks = 0; ks < 2; ++ks) {
      bf16x8 kf[4];
#pragma unroll
      for (int mf = 0; mf < 4; ++mf) {
        const int key = mf * 16 + lq;
        const int chunk = (lg + 4 * ks) ^ (key & 7);
        kf[mf] = *(const bf16x8*)(kb + key * 128 + chunk * 16);
      }
#pragma unroll
      for (int mf = 0; mf < 4; ++mf)
        s[mf] = __builtin_amdgcn_mfma_f32_16x16x32_bf16(kf[mf], qf[ks], s[mf], 0, 0, 0);
    }
    __builtin_amdgcn_s_setprio(0);

    // online softmax, log2 domain; mask only on the diagonal tile
    float sv[16];
    if (kt == qt) {
      const int th = w * 16 + lq;            // qrow - q0 (= qrow - k0 here)
#pragma unroll
      for (int mf = 0; mf < 4; ++mf)
#pragma unroll
        for (int r = 0; r < 4; ++r) {
          float x = s[mf][r];
          if (mf * 16 + lg * 4 + r > th) x = -1e30f;
          sv[mf * 4 + r] = x;
        }
    } else {
#pragma unroll
      for (int mf = 0; mf < 4; ++mf)
#pragma unroll
        for (int r = 0; r < 4; ++r) sv[mf * 4 + r] = s[mf][r];
    }
    float t0 = fmaxf(fmaxf(sv[0], sv[1]), fmaxf(sv[2], sv[3]));
    float t1 = fmaxf(fmaxf(sv[4], sv[5]), fmaxf(sv[6], sv[7]));
    float t2 = fmaxf(fmaxf(sv[8], sv[9]), fmaxf(sv[10], sv[11]));
    float t3 = fmaxf(fmaxf(sv[12], sv[13]), fmaxf(sv[14], sv[15]));
    float tmax = fmaxf(fmaxf(t0, t1), fmaxf(t2, t3));
    tmax = fmaxf(tmax, __shfl_xor(tmax, 16));
    tmax = fmaxf(tmax, __shfl_xor(tmax, 32));

    if (!__all(tmax - mrun <= 8.f)) {        // defer-max: rescale rarely
      const float mnew = fmaxf(mrun, tmax);
      const float sc = __builtin_amdgcn_exp2f(mrun - mnew);
      lrun *= sc;
#pragma unroll
      for (int mf = 0; mf < 4; ++mf) {
        o[mf][0] *= sc; o[mf][1] *= sc; o[mf][2] *= sc; o[mf][3] *= sc;
      }
      mrun = mnew;
    }

    float rs = 0.f;
#pragma unroll
    for (int mf = 0; mf < 4; ++mf) {
      const float p0 = __builtin_amdgcn_exp2f(sv[mf * 4 + 0] - mrun);
      const float p1 = __builtin_amdgcn_exp2f(sv[mf * 4 + 1] - mrun);
      const float p2 = __builtin_amdgcn_exp2f(sv[mf * 4 + 2] - mrun);
      const float p3 = __builtin_amdgcn_exp2f(sv[mf * 4 + 3] - mrun);
      rs += (p0 + p1) + (p2 + p3);
      uint2 pk;
      pk.x = pk2bf(p0, p1);
      pk.y = pk2bf(p2, p3);
      *(uint2*)&Pl[w][lq][mf * 16 + lg * 4] = pk;
    }
    rs += __shfl_xor(rs, 16);
    rs += __shfl_xor(rs, 32);
    lrun += rs;

    // O^T += V^T * P^T   (per-wave Pl strip: same-wave write->read)
    __builtin_amdgcn_s_setprio(1);
#pragma unroll
    for (int ks = 0; ks < 2; ++ks) {
      const bf16x8 pf = *(const bf16x8*)&Pl[w][lq][ks * 32 + lg * 8];
      bf16x8 vf[4];
#pragma unroll
      for (int mf = 0; mf < 4; ++mf) {
        const int d = mf * 16 + lq;
        const int chunk = (lg + 4 * ks) ^ (d & 7);
        vf[mf] = *(const bf16x8*)(vb + d * 128 + chunk * 16);
      }
#pragma unroll
      for (int mf = 0; mf < 4; ++mf)
        o[mf] = __builtin_amdgcn_mfma_f32_16x16x32_bf16(vf[mf], pf, o[mf], 0, 0, 0);
    }
    __builtin_amdgcn_s_setprio(0);
  }

  // epilogue: concat[b][qrow][h*64 + d], d = 16mf + 4lg + r
  const float inv = 1.f / lrun;
#pragma unroll
  for (int mf = 0; mf < 4; ++mf) {
    uint2 ov;
    ov.x = pk2bf(o[mf][0] * inv, o[mf][1] * inv);
    ov.y = pk2bf(o[mf][2] * inv, o[mf][3] * inv);
    *(uint2*)(concat + (size_t)(b * L_SEQ + qrow) * D_MODEL + h * HKD +
              mf * 16 + lg * 4) = ov;
  }
}

// ---------------------------------------------------------------------------
extern "C" void kernel_launch(void* const* d_in, const int* in_sizes, int n_in,
                              void* d_out, int out_size, void* d_ws, size_t ws_size,
                              hipStream_t stream) {
  const float* x    = (const float*)d_in[0];  // (2, 2048, 1024)
  const float* wqkv = (const float*)d_in[1];  // (1024, 3072)
  const float* wend = (const float*)d_in[2];  // (1024, 1024)
  float* out = (float*)d_out;                 // (2, 2048, 1024) fp32

  char* ws = (char*)d_ws;
  unsigned short* qkv   = (unsigned short*)(ws);              // 24 MB bf16
  unsigned short* xb    = (unsigned short*)(ws + 25165824);   //  8 MB (dead after GEMM1 -> vT)
  unsigned short* wqkvT = (unsigned short*)(ws + 33554432);   //  6 MB [3072][1024]
  unsigned short* wendT = (unsigned short*)(ws + 39845888);   //  2 MB [1024][1024]
  unsigned short* cat   = (unsigned short*)(ws + 41943040);   //  8 MB
  unsigned short* vT    = xb;                                 //  8 MB [32][64][2048]

  cvt_f32_bf16<<<2048, 256, 0, stream>>>(x, xb);
  transpose_cvt<<<dim3(48, 16), 256, 0, stream>>>(wqkv, wqkvT, 1024, 3072);
  transpose_cvt<<<dim3(16, 16), 256, 0, stream>>>(wend, wendT, 1024, 1024);

  // qkv = x @ wqkv   (M=4096, N=3072, K=1024) -> bf16
  gemm_bf16<unsigned short><<<dim3(24, 32), 256, 0, stream>>>(
      xb, wqkvT, qkv, 4096, 3072, 1024);
  // V^T pre-transpose (xb dead; vT aliases it)
  transpose_v<<<dim3(32, 32), 256, 0, stream>>>(qkv, vT);
  // flash attention -> concat bf16
  attn_mfma<<<dim3(32, 32), 256, 0, stream>>>(qkv, vT, cat);
  // out = concat @ wend  (M=4096, N=1024, K=1024) -> fp32
  gemm_bf16<float><<<dim3(8, 32), 256, 0, stream>>>(
      cat, wendT, out, 4096, 1024, 1024);
}

// Round 8
// 219.591 us; speedup vs baseline: 1.1317x; 1.1317x over previous
//
#include <hip/hip_runtime.h>
#include <hip/hip_bf16.h>
#include <cstddef>
#include <cstdint>

// (B, L, D, H) = (2, 2048, 1024, 16), KD = 64.
#define L_SEQ   2048
#define D_MODEL 1024
#define NH      16
#define HKD     64
#define TD3     3072
#define NBATCH  2

typedef __attribute__((ext_vector_type(8))) short bf16x8;
typedef __attribute__((ext_vector_type(4))) float f32x4;

__device__ __forceinline__ unsigned short f2bf(float f) {
  unsigned int u = __float_as_uint(f);
  u += 0x7fffu + ((u >> 16) & 1u);   // round-to-nearest-even
  return (unsigned short)(u >> 16);
}

__device__ __forceinline__ unsigned int pk2bf(float a, float b) {
  union { __hip_bfloat162 h; unsigned int u; } cv;
  cv.h = __float22bfloat162_rn(make_float2(a, b));
  return cv.u;
}

__device__ __forceinline__ void gll16(const void* g, void* l) {
  __builtin_amdgcn_global_load_lds(
      (const __attribute__((address_space(1))) unsigned int*)g,
      (__attribute__((address_space(3))) unsigned int*)l, 16, 0, 0);
}

// ---------------------------------------------------------------------------
// fp32 -> bf16, 8 elems/thread
// ---------------------------------------------------------------------------
__global__ __launch_bounds__(256)
void cvt_f32_bf16(const float* __restrict__ in, unsigned short* __restrict__ out) {
  const int i = blockIdx.x * 256 + threadIdx.x;
  const float4 a = ((const float4*)in)[2 * i];
  const float4 b = ((const float4*)in)[2 * i + 1];
  bf16x8 v;
  v[0] = (short)f2bf(a.x); v[1] = (short)f2bf(a.y);
  v[2] = (short)f2bf(a.z); v[3] = (short)f2bf(a.w);
  v[4] = (short)f2bf(b.x); v[5] = (short)f2bf(b.y);
  v[6] = (short)f2bf(b.z); v[7] = (short)f2bf(b.w);
  ((bf16x8*)out)[i] = v;
}

// ---------------------------------------------------------------------------
// W[K][N] fp32 -> WT[N][K] bf16 (64x64 tiles through LDS)
// ---------------------------------------------------------------------------
__global__ __launch_bounds__(256)
void transpose_cvt(const float* __restrict__ W, unsigned short* __restrict__ WT,
                   int K, int N) {
  __shared__ unsigned short T[64][68];
  const int t = threadIdx.x;
  const int n0 = blockIdx.x * 64, k0 = blockIdx.y * 64;
  const int cr = t >> 4, cc = (t & 15) * 4;
#pragma unroll
  for (int i = 0; i < 4; ++i) {
    const int k = cr + 16 * i;
    const float4 v = *(const float4*)(W + (size_t)(k0 + k) * N + n0 + cc);
    T[cc + 0][k] = f2bf(v.x); T[cc + 1][k] = f2bf(v.y);
    T[cc + 2][k] = f2bf(v.z); T[cc + 3][k] = f2bf(v.w);
  }
  __syncthreads();
#pragma unroll
  for (int i = 0; i < 4; ++i) {
    const int n = cr + 16 * i;
    ushort4 o;
    o.x = T[n][cc]; o.y = T[n][cc + 1]; o.z = T[n][cc + 2]; o.w = T[n][cc + 3];
    *(ushort4*)(WT + (size_t)(n0 + n) * K + k0 + cc) = o;
  }
}

// ---------------------------------------------------------------------------
// bf16 MFMA GEMM, m97-style: C[M,N] = A[M,K] * Bt[N,K]^T.
// 128x128 tile, BK=64, 256 threads (4 waves, 2x2), 4x4 16x16x32 frags/wave.
// XCD-aware bijective block swizzle (grid multiple of 8).
// ---------------------------------------------------------------------------
template <typename OUT>
__device__ __forceinline__ OUT cvt_out(float f);
template <> __device__ __forceinline__ float cvt_out<float>(float f) { return f; }
template <> __device__ __forceinline__ unsigned short cvt_out<unsigned short>(float f) { return f2bf(f); }

template <typename OUT>
__global__ __launch_bounds__(256)
void gemm_bf16(const unsigned short* __restrict__ A,   // [M][K] bf16
               const unsigned short* __restrict__ Bt,  // [N][K] bf16
               OUT* __restrict__ C, int M, int N, int K) {
  __shared__ unsigned short As[128 * 64];
  __shared__ unsigned short Bs[128 * 64];
  const int t = threadIdx.x, w = t >> 6, lane = t & 63;
  const int lg = lane >> 4, lq = lane & 15;

  // XCD swizzle: contiguous chunk of blocks per XCD (nwg % 8 == 0)
  const int nwg = gridDim.x * gridDim.y;
  int bid = blockIdx.y * gridDim.x + blockIdx.x;
  bid = (bid & 7) * (nwg >> 3) + (bid >> 3);
  const int m0 = (bid / gridDim.x) * 128, n0 = (bid % gridDim.x) * 128;
  const int wr = w >> 1, wc = w & 1;

  f32x4 acc[4][4];
#pragma unroll
  for (int a = 0; a < 4; ++a)
#pragma unroll
    for (int b = 0; b < 4; ++b) acc[a][b] = (f32x4)0.f;

  for (int k0 = 0; k0 < K; k0 += 64) {
    __syncthreads();  // previous iteration's LDS reads done
#pragma unroll
    for (int i = 0; i < 4; ++i) {
      const int c = 256 * i + t;            // chunk 0..1023 (16B each)
      const int row = c >> 3, cc = (c & 7) * 8;
      gll16(A + (size_t)(m0 + row) * K + k0 + cc,
            (char*)As + (256 * i + 64 * w) * 16);
      gll16(Bt + (size_t)(n0 + row) * K + k0 + cc,
            (char*)Bs + (256 * i + 64 * w) * 16);
    }
    __syncthreads();  // drains vmcnt -> tiles ready
#pragma unroll
    for (int ks = 0; ks < 2; ++ks) {
      bf16x8 af[4], bfr[4];
#pragma unroll
      for (int mf = 0; mf < 4; ++mf)
        af[mf] = *(const bf16x8*)((const char*)As +
                   (wr * 64 + mf * 16 + lq) * 128 + ks * 64 + lg * 16);
#pragma unroll
      for (int nf = 0; nf < 4; ++nf)
        bfr[nf] = *(const bf16x8*)((const char*)Bs +
                   (wc * 64 + nf * 16 + lq) * 128 + ks * 64 + lg * 16);
#pragma unroll
      for (int mf = 0; mf < 4; ++mf)
#pragma unroll
        for (int nf = 0; nf < 4; ++nf)
          acc[mf][nf] = __builtin_amdgcn_mfma_f32_16x16x32_bf16(
              af[mf], bfr[nf], acc[mf][nf], 0, 0, 0);
    }
  }

  // C/D layout: col = lane&15, row = (lane>>4)*4 + reg  [m89]
#pragma unroll
  for (int mf = 0; mf < 4; ++mf)
#pragma unroll
    for (int nf = 0; nf < 4; ++nf) {
      const int col = n0 + wc * 64 + nf * 16 + lq;
#pragma unroll
      for (int r = 0; r < 4; ++r) {
        const int row = m0 + wr * 64 + mf * 16 + lg * 4 + r;
        C[(size_t)row * N + col] = cvt_out<OUT>(acc[mf][nf][r]);
      }
    }
}

// ---------------------------------------------------------------------------
// Reference's direct reshape: head h, attn row s <-> memory row h*128 + s/16,
// cols (s%16)*64 (+ part*D_MODEL).
// ---------------------------------------------------------------------------
__device__ __forceinline__ size_t head_row(int part, int b, int h, int s) {
  return ((size_t)(b * L_SEQ + h * 128 + (s >> 4))) * TD3 +
         (size_t)part * D_MODEL + (size_t)(s & 15) * HKD;
}

// ---------------------------------------------------------------------------
// V pre-transpose: vT[b][h][d][s]
// ---------------------------------------------------------------------------
__global__ __launch_bounds__(256)
void transpose_v(const unsigned short* __restrict__ qkv,
                 unsigned short* __restrict__ vT) {
  __shared__ unsigned short T[64][68];
  const int t = threadIdx.x;
  const int kt = blockIdx.x, bh = blockIdx.y, b = bh >> 4, h = bh & 15;
  const int s0 = kt * 64;
  const int sr = t >> 4, c4 = (t & 15) * 4;
#pragma unroll
  for (int i = 0; i < 4; ++i) {
    const int s = sr + 16 * i;
    const ushort4 v = *(const ushort4*)(qkv + head_row(2, b, h, s0 + s) + c4);
    T[c4 + 0][s] = v.x; T[c4 + 1][s] = v.y;
    T[c4 + 2][s] = v.z; T[c4 + 3][s] = v.w;
  }
  __syncthreads();
#pragma unroll
  for (int i = 0; i < 4; ++i) {
    const int d = sr + 16 * i;
    ushort4 o;
    o.x = T[d][c4]; o.y = T[d][c4 + 1]; o.z = T[d][c4 + 2]; o.w = T[d][c4 + 3];
    *(ushort4*)(vT + ((size_t)(bh * 64 + d)) * L_SEQ + s0 + c4) = o;
  }
}

// ---------------------------------------------------------------------------
// MFMA flash attention. QBLK=128 (8 waves), KVBLK=64, double-buffered K/V^T
// via global_load_lds (prefetch hides under compute). Swapped operands:
// S^T = mfma(K, Q^T), O^T = mfma(V^T, P^T). Log2-domain softmax, wave-uniform
// diag masking (bound = wave MIN q-row), defer-max, masked-wave skip,
// bh->XCD clustered launch.
// ---------------------------------------------------------------------------
#define QK_SCALE 0.18033688011112043f   // log2(e)/8

__global__ __launch_bounds__(512)
void attn_mfma(const unsigned short* __restrict__ qkv,
               const unsigned short* __restrict__ vT,
               unsigned short* __restrict__ concat) {
  __shared__ unsigned short Ks[2][64 * 64];  // [key][d], chunk-XOR swizzled
  __shared__ unsigned short Vs[2][64 * 64];  // [d][key], chunk-XOR swizzled
  __shared__ unsigned short Pl[8][16][72];   // per-wave P[q][key], padded

  const int t = threadIdx.x, w = t >> 6, lane = t & 63;
  const int lg = lane >> 4, lq = lane & 15;

  // bh->XCD clustering: hardware XCD = dispatch_id % 8 (round-robin).
  // Each XCD handles bh in {xcd, xcd+8, xcd+16, xcd+24}; qt heavy-first.
  const int bid = blockIdx.x;
  const int xcd = bid & 7, idx = bid >> 3;       // idx 0..63
  const int bh = xcd + 8 * (idx >> 4);
  const int qt = 15 - (idx & 15);
  const int b = bh >> 4, h = bh & 15;
  const int q0 = qt * 128;
  const int qrow = q0 + w * 16 + lq;             // this lane's q row

  // Q fragments, pre-scaled by log2(e)/sqrt(KD) (softmax in log2 domain)
  bf16x8 qf[2];
  {
    const size_t qb = head_row(0, b, h, qrow) + lg * 8;
    qf[0] = *(const bf16x8*)(qkv + qb);
    qf[1] = *(const bf16x8*)(qkv + qb + 32);
#pragma unroll
    for (int s = 0; s < 2; ++s)
#pragma unroll
      for (int j = 0; j < 8; ++j) {
        const float f =
            __uint_as_float(((unsigned int)(unsigned short)qf[s][j]) << 16);
        qf[s][j] = (short)f2bf(f * QK_SCALE);
      }
  }

  // staging: thread t stages 16B chunk t of each 64x64 tile.
  // dest linear; source column XOR-swizzled (involution; reads apply same).
  const int srow = t >> 3;                       // 0..63
  const int swz = ((t & 7) ^ (srow & 7)) * 8;
  const size_t kSrc = head_row(1, b, h, srow) + swz;            // += k0*192
  const size_t vSrc = ((size_t)(bh * 64 + srow)) * L_SEQ + swz; // += k0
  char* const kDst = (char*)&Ks[0][0] + w * 1024;
  char* const vDst = (char*)&Vs[0][0] + w * 1024;

  f32x4 o[4];
#pragma unroll
  for (int mf = 0; mf < 4; ++mf) o[mf] = (f32x4)0.f;
  float mrun = -1e30f, lrun = 0.f;

  const int ktmax = 2 * qt + 1;

  // prologue: stage tile 0 into buffer 0
  gll16(qkv + kSrc, kDst);
  gll16(vT + vSrc, vDst);

  for (int kt = 0; kt <= ktmax; ++kt) {
    const int k0 = kt * 64;
    const int cur = kt & 1;
    __syncthreads();  // vmcnt drained: buf[cur] ready; buf[1-cur] reads done

    if (kt < ktmax) {  // prefetch next tile into other buffer (overlaps compute)
      gll16(qkv + kSrc + (size_t)(k0 + 64) * 192, kDst + (1 - cur) * 8192);
      gll16(vT + vSrc + (size_t)(k0 + 64), vDst + (1 - cur) * 8192);
    }

    // waves whose q-strip lies entirely above this K-tile skip all compute
    if (k0 > q0 + w * 16 + 15) continue;

    const char* kb = (const char*)&Ks[cur][0];
    const char* vb = (const char*)&Vs[cur][0];

    // S^T = K * Q^T : lane holds S^T[key=16mf+4lg+r][q=lq] (log2-scaled)
    f32x4 s[4];
#pragma unroll
    for (int mf = 0; mf < 4; ++mf) s[mf] = (f32x4)0.f;
    __builtin_amdgcn_s_setprio(1);
#pragma unroll
    for (int ks = 0; ks < 2; ++ks) {
      bf16x8 kf[4];
#pragma unroll
      for (int mf = 0; mf < 4; ++mf) {
        const int key = mf * 16 + lq;
        const int chunk = (lg + 4 * ks) ^ (key & 7);
        kf[mf] = *(const bf16x8*)(kb + key * 128 + chunk * 16);
      }
#pragma unroll
      for (int mf = 0; mf < 4; ++mf)
        s[mf] = __builtin_amdgcn_mfma_f32_16x16x32_bf16(kf[mf], qf[ks], s[mf], 0, 0, 0);
    }
    __builtin_amdgcn_s_setprio(0);

    // online softmax, log2 domain.
    // Mask needed iff tile max key (k0+63) exceeds wave MIN q-row (qrow-lq).
    // (R6 bug: compared against wave MAX q-row -> diagonal tile unmasked.)
    float sv[16];
    if (k0 + 63 > qrow - lq) {                 // wave-uniform
#pragma unroll
      for (int mf = 0; mf < 4; ++mf)
#pragma unroll
        for (int r = 0; r < 4; ++r) {
          float x = s[mf][r];
          if (k0 + mf * 16 + lg * 4 + r > qrow) x = -1e30f;
          sv[mf * 4 + r] = x;
        }
    } else {
#pragma unroll
      for (int mf = 0; mf < 4; ++mf)
#pragma unroll
        for (int r = 0; r < 4; ++r) sv[mf * 4 + r] = s[mf][r];
    }
    float t0 = fmaxf(fmaxf(sv[0], sv[1]), fmaxf(sv[2], sv[3]));
    float t1 = fmaxf(fmaxf(sv[4], sv[5]), fmaxf(sv[6], sv[7]));
    float t2 = fmaxf(fmaxf(sv[8], sv[9]), fmaxf(sv[10], sv[11]));
    float t3 = fmaxf(fmaxf(sv[12], sv[13]), fmaxf(sv[14], sv[15]));
    float tmax = fmaxf(fmaxf(t0, t1), fmaxf(t2, t3));
    tmax = fmaxf(tmax, __shfl_xor(tmax, 16));
    tmax = fmaxf(tmax, __shfl_xor(tmax, 32));

    if (!__all(tmax - mrun <= 8.f)) {          // defer-max: rescale rarely
      const float mnew = fmaxf(mrun, tmax);
      const float sc = __builtin_amdgcn_exp2f(mrun - mnew);
      lrun *= sc;
#pragma unroll
      for (int mf = 0; mf < 4; ++mf) {
        o[mf][0] *= sc; o[mf][1] *= sc; o[mf][2] *= sc; o[mf][3] *= sc;
      }
      mrun = mnew;
    }

    float rs = 0.f;
#pragma unroll
    for (int mf = 0; mf < 4; ++mf) {
      const float p0 = __builtin_amdgcn_exp2f(sv[mf * 4 + 0] - mrun);
      const float p1 = __builtin_amdgcn_exp2f(sv[mf * 4 + 1] - mrun);
      const float p2 = __builtin_amdgcn_exp2f(sv[mf * 4 + 2] - mrun);
      const float p3 = __builtin_amdgcn_exp2f(sv[mf * 4 + 3] - mrun);
      rs += (p0 + p1) + (p2 + p3);
      uint2 pk;
      pk.x = pk2bf(p0, p1);
      pk.y = pk2bf(p2, p3);
      *(uint2*)&Pl[w][lq][mf * 16 + lg * 4] = pk;
    }
    rs += __shfl_xor(rs, 16);
    rs += __shfl_xor(rs, 32);
    lrun += rs;

    // O^T += V^T * P^T   (per-wave Pl strip: same-wave write->read)
    __builtin_amdgcn_s_setprio(1);
#pragma unroll
    for (int ks = 0; ks < 2; ++ks) {
      const bf16x8 pf = *(const bf16x8*)&Pl[w][lq][ks * 32 + lg * 8];
      bf16x8 vf[4];
#pragma unroll
      for (int mf = 0; mf < 4; ++mf) {
        const int d = mf * 16 + lq;
        const int chunk = (lg + 4 * ks) ^ (d & 7);
        vf[mf] = *(const bf16x8*)(vb + d * 128 + chunk * 16);
      }
#pragma unroll
      for (int mf = 0; mf < 4; ++mf)
        o[mf] = __builtin_amdgcn_mfma_f32_16x16x32_bf16(vf[mf], pf, o[mf], 0, 0, 0);
    }
    __builtin_amdgcn_s_setprio(0);
  }

  // epilogue: concat[b][qrow][h*64 + d], d = 16mf + 4lg + r
  const float inv = 1.f / lrun;
#pragma unroll
  for (int mf = 0; mf < 4; ++mf) {
    uint2 ov;
    ov.x = pk2bf(o[mf][0] * inv, o[mf][1] * inv);
    ov.y = pk2bf(o[mf][2] * inv, o[mf][3] * inv);
    *(uint2*)(concat + (size_t)(b * L_SEQ + qrow) * D_MODEL + h * HKD +
              mf * 16 + lg * 4) = ov;
  }
}

// ---------------------------------------------------------------------------
extern "C" void kernel_launch(void* const* d_in, const int* in_sizes, int n_in,
                              void* d_out, int out_size, void* d_ws, size_t ws_size,
                              hipStream_t stream) {
  const float* x    = (const float*)d_in[0];  // (2, 2048, 1024)
  const float* wqkv = (const float*)d_in[1];  // (1024, 3072)
  const float* wend = (const float*)d_in[2];  // (1024, 1024)
  float* out = (float*)d_out;                 // (2, 2048, 1024) fp32

  char* ws = (char*)d_ws;
  unsigned short* qkv   = (unsigned short*)(ws);              // 24 MB bf16
  unsigned short* xb    = (unsigned short*)(ws + 25165824);   //  8 MB (dead after GEMM1 -> vT)
  unsigned short* wqkvT = (unsigned short*)(ws + 33554432);   //  6 MB [3072][1024]
  unsigned short* wendT = (unsigned short*)(ws + 39845888);   //  2 MB [1024][1024]
  unsigned short* cat   = (unsigned short*)(ws + 41943040);   //  8 MB
  unsigned short* vT    = xb;                                 //  8 MB [32][64][2048]

  cvt_f32_bf16<<<2048, 256, 0, stream>>>(x, xb);
  transpose_cvt<<<dim3(48, 16), 256, 0, stream>>>(wqkv, wqkvT, 1024, 3072);
  transpose_cvt<<<dim3(16, 16), 256, 0, stream>>>(wend, wendT, 1024, 1024);

  // qkv = x @ wqkv   (M=4096, N=3072, K=1024) -> bf16
  gemm_bf16<unsigned short><<<dim3(24, 32), 256, 0, stream>>>(
      xb, wqkvT, qkv, 4096, 3072, 1024);
  // V^T pre-transpose (xb dead; vT aliases it)
  transpose_v<<<dim3(32, 32), 256, 0, stream>>>(qkv, vT);
  // flash attention -> concat bf16
  attn_mfma<<<512, 512, 0, stream>>>(qkv, vT, cat);
  // out = concat @ wend  (M=4096, N=1024, K=1024) -> fp32
  gemm_bf16<float><<<dim3(8, 32), 256, 0, stream>>>(
      cat, wendT, out, 4096, 1024, 1024);
}

// Round 9
// 212.438 us; speedup vs baseline: 1.1698x; 1.0337x over previous
//
#include <hip/hip_runtime.h>
#include <hip/hip_bf16.h>
#include <cstddef>
#include <cstdint>

// (B, L, D, H) = (2, 2048, 1024, 16), KD = 64.
#define L_SEQ   2048
#define D_MODEL 1024
#define NH      16
#define HKD     64
#define TD3     3072
#define NBATCH  2

typedef __attribute__((ext_vector_type(8))) short bf16x8;
typedef __attribute__((ext_vector_type(4))) float f32x4;

__device__ __forceinline__ unsigned short f2bf(float f) {
  unsigned int u = __float_as_uint(f);
  u += 0x7fffu + ((u >> 16) & 1u);   // round-to-nearest-even
  return (unsigned short)(u >> 16);
}

__device__ __forceinline__ unsigned int pk2bf(float a, float b) {
  union { __hip_bfloat162 h; unsigned int u; } cv;
  cv.h = __float22bfloat162_rn(make_float2(a, b));
  return cv.u;
}

__device__ __forceinline__ void gll16(const void* g, void* l) {
  __builtin_amdgcn_global_load_lds(
      (const __attribute__((address_space(1))) unsigned int*)g,
      (__attribute__((address_space(3))) unsigned int*)l, 16, 0, 0);
}

// ---------------------------------------------------------------------------
// fp32 -> bf16, 8 elems/thread
// ---------------------------------------------------------------------------
__global__ __launch_bounds__(256)
void cvt_f32_bf16(const float* __restrict__ in, unsigned short* __restrict__ out) {
  const int i = blockIdx.x * 256 + threadIdx.x;
  const float4 a = ((const float4*)in)[2 * i];
  const float4 b = ((const float4*)in)[2 * i + 1];
  bf16x8 v;
  v[0] = (short)f2bf(a.x); v[1] = (short)f2bf(a.y);
  v[2] = (short)f2bf(a.z); v[3] = (short)f2bf(a.w);
  v[4] = (short)f2bf(b.x); v[5] = (short)f2bf(b.y);
  v[6] = (short)f2bf(b.z); v[7] = (short)f2bf(b.w);
  ((bf16x8*)out)[i] = v;
}

// ---------------------------------------------------------------------------
// W[K][N] fp32 -> WT[N][K] bf16 (64x64 tiles through LDS)
// ---------------------------------------------------------------------------
__global__ __launch_bounds__(256)
void transpose_cvt(const float* __restrict__ W, unsigned short* __restrict__ WT,
                   int K, int N) {
  __shared__ unsigned short T[64][68];
  const int t = threadIdx.x;
  const int n0 = blockIdx.x * 64, k0 = blockIdx.y * 64;
  const int cr = t >> 4, cc = (t & 15) * 4;
#pragma unroll
  for (int i = 0; i < 4; ++i) {
    const int k = cr + 16 * i;
    const float4 v = *(const float4*)(W + (size_t)(k0 + k) * N + n0 + cc);
    T[cc + 0][k] = f2bf(v.x); T[cc + 1][k] = f2bf(v.y);
    T[cc + 2][k] = f2bf(v.z); T[cc + 3][k] = f2bf(v.w);
  }
  __syncthreads();
#pragma unroll
  for (int i = 0; i < 4; ++i) {
    const int n = cr + 16 * i;
    ushort4 o;
    o.x = T[n][cc]; o.y = T[n][cc + 1]; o.z = T[n][cc + 2]; o.w = T[n][cc + 3];
    *(ushort4*)(WT + (size_t)(n0 + n) * K + k0 + cc) = o;
  }
}

// ---------------------------------------------------------------------------
// bf16 MFMA GEMM, m97-style: C[M,N] = A[M,K] * Bt[N,K]^T.
// 128x128 tile, BK=64, 256 threads (4 waves, 2x2), 4x4 16x16x32 frags/wave.
// XCD-aware bijective block swizzle (grid multiple of 8).
// ---------------------------------------------------------------------------
template <typename OUT>
__device__ __forceinline__ OUT cvt_out(float f);
template <> __device__ __forceinline__ float cvt_out<float>(float f) { return f; }
template <> __device__ __forceinline__ unsigned short cvt_out<unsigned short>(float f) { return f2bf(f); }

template <typename OUT>
__global__ __launch_bounds__(256)
void gemm_bf16(const unsigned short* __restrict__ A,   // [M][K] bf16
               const unsigned short* __restrict__ Bt,  // [N][K] bf16
               OUT* __restrict__ C, int M, int N, int K) {
  __shared__ unsigned short As[128 * 64];
  __shared__ unsigned short Bs[128 * 64];
  const int t = threadIdx.x, w = t >> 6, lane = t & 63;
  const int lg = lane >> 4, lq = lane & 15;

  // XCD swizzle: contiguous chunk of blocks per XCD (nwg % 8 == 0)
  const int nwg = gridDim.x * gridDim.y;
  int bid = blockIdx.y * gridDim.x + blockIdx.x;
  bid = (bid & 7) * (nwg >> 3) + (bid >> 3);
  const int m0 = (bid / gridDim.x) * 128, n0 = (bid % gridDim.x) * 128;
  const int wr = w >> 1, wc = w & 1;

  f32x4 acc[4][4];
#pragma unroll
  for (int a = 0; a < 4; ++a)
#pragma unroll
    for (int b = 0; b < 4; ++b) acc[a][b] = (f32x4)0.f;

  for (int k0 = 0; k0 < K; k0 += 64) {
    __syncthreads();  // previous iteration's LDS reads done
#pragma unroll
    for (int i = 0; i < 4; ++i) {
      const int c = 256 * i + t;            // chunk 0..1023 (16B each)
      const int row = c >> 3, cc = (c & 7) * 8;
      gll16(A + (size_t)(m0 + row) * K + k0 + cc,
            (char*)As + (256 * i + 64 * w) * 16);
      gll16(Bt + (size_t)(n0 + row) * K + k0 + cc,
            (char*)Bs + (256 * i + 64 * w) * 16);
    }
    __syncthreads();  // drains vmcnt -> tiles ready
#pragma unroll
    for (int ks = 0; ks < 2; ++ks) {
      bf16x8 af[4], bfr[4];
#pragma unroll
      for (int mf = 0; mf < 4; ++mf)
        af[mf] = *(const bf16x8*)((const char*)As +
                   (wr * 64 + mf * 16 + lq) * 128 + ks * 64 + lg * 16);
#pragma unroll
      for (int nf = 0; nf < 4; ++nf)
        bfr[nf] = *(const bf16x8*)((const char*)Bs +
                   (wc * 64 + nf * 16 + lq) * 128 + ks * 64 + lg * 16);
#pragma unroll
      for (int mf = 0; mf < 4; ++mf)
#pragma unroll
        for (int nf = 0; nf < 4; ++nf)
          acc[mf][nf] = __builtin_amdgcn_mfma_f32_16x16x32_bf16(
              af[mf], bfr[nf], acc[mf][nf], 0, 0, 0);
    }
  }

  // C/D layout: col = lane&15, row = (lane>>4)*4 + reg  [m89]
#pragma unroll
  for (int mf = 0; mf < 4; ++mf)
#pragma unroll
    for (int nf = 0; nf < 4; ++nf) {
      const int col = n0 + wc * 64 + nf * 16 + lq;
#pragma unroll
      for (int r = 0; r < 4; ++r) {
        const int row = m0 + wr * 64 + mf * 16 + lg * 4 + r;
        C[(size_t)row * N + col] = cvt_out<OUT>(acc[mf][nf][r]);
      }
    }
}

// ---------------------------------------------------------------------------
// Reference's direct reshape: head h, attn row s <-> memory row h*128 + s/16,
// cols (s%16)*64 (+ part*D_MODEL).
// ---------------------------------------------------------------------------
__device__ __forceinline__ size_t head_row(int part, int b, int h, int s) {
  return ((size_t)(b * L_SEQ + h * 128 + (s >> 4))) * TD3 +
         (size_t)part * D_MODEL + (size_t)(s & 15) * HKD;
}

// ---------------------------------------------------------------------------
// V pre-transpose: vT[b][h][d][s]
// ---------------------------------------------------------------------------
__global__ __launch_bounds__(256)
void transpose_v(const unsigned short* __restrict__ qkv,
                 unsigned short* __restrict__ vT) {
  __shared__ unsigned short T[64][68];
  const int t = threadIdx.x;
  const int kt = blockIdx.x, bh = blockIdx.y, b = bh >> 4, h = bh & 15;
  const int s0 = kt * 64;
  const int sr = t >> 4, c4 = (t & 15) * 4;
#pragma unroll
  for (int i = 0; i < 4; ++i) {
    const int s = sr + 16 * i;
    const ushort4 v = *(const ushort4*)(qkv + head_row(2, b, h, s0 + s) + c4);
    T[c4 + 0][s] = v.x; T[c4 + 1][s] = v.y;
    T[c4 + 2][s] = v.z; T[c4 + 3][s] = v.w;
  }
  __syncthreads();
#pragma unroll
  for (int i = 0; i < 4; ++i) {
    const int d = sr + 16 * i;
    ushort4 o;
    o.x = T[d][c4]; o.y = T[d][c4 + 1]; o.z = T[d][c4 + 2]; o.w = T[d][c4 + 3];
    *(ushort4*)(vT + ((size_t)(bh * 64 + d)) * L_SEQ + s0 + c4) = o;
  }
}

// ---------------------------------------------------------------------------
// MFMA flash attention. Each block processes TWO q-blocks sequentially:
// qt_hi = 15-p then qt_lo = p  ->  every block = exactly 34 K/V tiles
// (perfect load balance, scheduler-independent). 8 waves, QBLK=128/pass,
// KVBLK=64, dbuf K/V^T via global_load_lds. Swapped operands:
// S^T = mfma(K, Q^T), O^T = mfma(V^T, P^T). Log2-domain softmax, wave-uniform
// diag masking, defer-max, masked-wave skip, bh->XCD clustered launch.
// ---------------------------------------------------------------------------
#define QK_SCALE 0.18033688011112043f   // log2(e)/8

__global__ __launch_bounds__(512)
void attn_mfma(const unsigned short* __restrict__ qkv,
               const unsigned short* __restrict__ vT,
               unsigned short* __restrict__ concat) {
  __shared__ unsigned short Ks[2][64 * 64];  // [key][d], chunk-XOR swizzled
  __shared__ unsigned short Vs[2][64 * 64];  // [d][key], chunk-XOR swizzled
  __shared__ unsigned short Pl[8][16][72];   // per-wave P[q][key], padded

  const int t = threadIdx.x, w = t >> 6, lane = t & 63;
  const int lg = lane >> 4, lq = lane & 15;

  // 256 blocks: xcd = bid&7 (round-robin XCD), per XCD 4 bh x 8 pairs.
  const int bid = blockIdx.x;
  const int xcd = bid & 7, idx = bid >> 3;       // idx 0..31
  const int bh = xcd + 8 * (idx & 3);
  const int pair = idx >> 2;                     // 0..7
  const int b = bh >> 4, h = bh & 15;

  // staging: thread t stages 16B chunk t of each 64x64 tile.
  // dest linear; source column XOR-swizzled (involution; reads apply same).
  const int srow = t >> 3;                       // 0..63
  const int swz = ((t & 7) ^ (srow & 7)) * 8;
  const size_t kSrc = head_row(1, b, h, srow) + swz;            // += k0*192
  const size_t vSrc = ((size_t)(bh * 64 + srow)) * L_SEQ + swz; // += k0
  char* const kDst = (char*)&Ks[0][0] + w * 1024;
  char* const vDst = (char*)&Vs[0][0] + w * 1024;

  for (int pass = 0; pass < 2; ++pass) {
    const int qt = pass ? pair : 15 - pair;      // qt_hi + qt_lo = 15
    const int q0 = qt * 128;
    const int qrow = q0 + w * 16 + lq;           // this lane's q row

    // Q fragments, pre-scaled by log2(e)/sqrt(KD) (softmax in log2 domain)
    bf16x8 qf[2];
    {
      const size_t qb = head_row(0, b, h, qrow) + lg * 8;
      qf[0] = *(const bf16x8*)(qkv + qb);
      qf[1] = *(const bf16x8*)(qkv + qb + 32);
#pragma unroll
      for (int s = 0; s < 2; ++s)
#pragma unroll
        for (int j = 0; j < 8; ++j) {
          const float f =
              __uint_as_float(((unsigned int)(unsigned short)qf[s][j]) << 16);
          qf[s][j] = (short)f2bf(f * QK_SCALE);
        }
    }

    f32x4 o[4];
#pragma unroll
    for (int mf = 0; mf < 4; ++mf) o[mf] = (f32x4)0.f;
    float mrun = -1e30f, lrun = 0.f;

    const int ktmax = 2 * qt + 1;

    __syncthreads();  // previous pass's LDS reads done before re-staging buf0
    // prologue: stage tile 0 into buffer 0
    gll16(qkv + kSrc, kDst);
    gll16(vT + vSrc, vDst);

    for (int kt = 0; kt <= ktmax; ++kt) {
      const int k0 = kt * 64;
      const int cur = kt & 1;
      __syncthreads();  // vmcnt drained: buf[cur] ready; buf[1-cur] reads done

      if (kt < ktmax) {  // prefetch next tile into other buffer
        gll16(qkv + kSrc + (size_t)(k0 + 64) * 192, kDst + (1 - cur) * 8192);
        gll16(vT + vSrc + (size_t)(k0 + 64), vDst + (1 - cur) * 8192);
      }

      // waves whose q-strip lies entirely above this K-tile skip all compute
      if (k0 > q0 + w * 16 + 15) continue;

      const char* kb = (const char*)&Ks[cur][0];
      const char* vb = (const char*)&Vs[cur][0];

      // S^T = K * Q^T : lane holds S^T[key=16mf+4lg+r][q=lq] (log2-scaled)
      f32x4 s[4];
#pragma unroll
      for (int mf = 0; mf < 4; ++mf) s[mf] = (f32x4)0.f;
      __builtin_amdgcn_s_setprio(1);
#pragma unroll
      for (int ks = 0; ks < 2; ++ks) {
        bf16x8 kf[4];
#pragma unroll
        for (int mf = 0; mf < 4; ++mf) {
          const int key = mf * 16 + lq;
          const int chunk = (lg + 4 * ks) ^ (key & 7);
          kf[mf] = *(const bf16x8*)(kb + key * 128 + chunk * 16);
        }
#pragma unroll
        for (int mf = 0; mf < 4; ++mf)
          s[mf] = __builtin_amdgcn_mfma_f32_16x16x32_bf16(kf[mf], qf[ks], s[mf], 0, 0, 0);
      }
      __builtin_amdgcn_s_setprio(0);

      // online softmax, log2 domain.
      // Mask needed iff tile max key (k0+63) exceeds wave MIN q-row (qrow-lq).
      float sv[16];
      if (k0 + 63 > qrow - lq) {                 // wave-uniform
#pragma unroll
        for (int mf = 0; mf < 4; ++mf)
#pragma unroll
          for (int r = 0; r < 4; ++r) {
            float x = s[mf][r];
            if (k0 + mf * 16 + lg * 4 + r > qrow) x = -1e30f;
            sv[mf * 4 + r] = x;
          }
      } else {
#pragma unroll
        for (int mf = 0; mf < 4; ++mf)
#pragma unroll
          for (int r = 0; r < 4; ++r) sv[mf * 4 + r] = s[mf][r];
      }
      float t0 = fmaxf(fmaxf(sv[0], sv[1]), fmaxf(sv[2], sv[3]));
      float t1 = fmaxf(fmaxf(sv[4], sv[5]), fmaxf(sv[6], sv[7]));
      float t2 = fmaxf(fmaxf(sv[8], sv[9]), fmaxf(sv[10], sv[11]));
      float t3 = fmaxf(fmaxf(sv[12], sv[13]), fmaxf(sv[14], sv[15]));
      float tmax = fmaxf(fmaxf(t0, t1), fmaxf(t2, t3));
      tmax = fmaxf(tmax, __shfl_xor(tmax, 16));
      tmax = fmaxf(tmax, __shfl_xor(tmax, 32));

      if (!__all(tmax - mrun <= 8.f)) {          // defer-max: rescale rarely
        const float mnew = fmaxf(mrun, tmax);
        const float sc = __builtin_amdgcn_exp2f(mrun - mnew);
        lrun *= sc;
#pragma unroll
        for (int mf = 0; mf < 4; ++mf) {
          o[mf][0] *= sc; o[mf][1] *= sc; o[mf][2] *= sc; o[mf][3] *= sc;
        }
        mrun = mnew;
      }

      float rs = 0.f;
#pragma unroll
      for (int mf = 0; mf < 4; ++mf) {
        const float p0 = __builtin_amdgcn_exp2f(sv[mf * 4 + 0] - mrun);
        const float p1 = __builtin_amdgcn_exp2f(sv[mf * 4 + 1] - mrun);
        const float p2 = __builtin_amdgcn_exp2f(sv[mf * 4 + 2] - mrun);
        const float p3 = __builtin_amdgcn_exp2f(sv[mf * 4 + 3] - mrun);
        rs += (p0 + p1) + (p2 + p3);
        uint2 pk;
        pk.x = pk2bf(p0, p1);
        pk.y = pk2bf(p2, p3);
        *(uint2*)&Pl[w][lq][mf * 16 + lg * 4] = pk;
      }
      rs += __shfl_xor(rs, 16);
      rs += __shfl_xor(rs, 32);
      lrun += rs;

      // O^T += V^T * P^T   (per-wave Pl strip: same-wave write->read)
      __builtin_amdgcn_s_setprio(1);
#pragma unroll
      for (int ks = 0; ks < 2; ++ks) {
        const bf16x8 pf = *(const bf16x8*)&Pl[w][lq][ks * 32 + lg * 8];
        bf16x8 vf[4];
#pragma unroll
        for (int mf = 0; mf < 4; ++mf) {
          const int d = mf * 16 + lq;
          const int chunk = (lg + 4 * ks) ^ (d & 7);
          vf[mf] = *(const bf16x8*)(vb + d * 128 + chunk * 16);
        }
#pragma unroll
        for (int mf = 0; mf < 4; ++mf)
          o[mf] = __builtin_amdgcn_mfma_f32_16x16x32_bf16(vf[mf], pf, o[mf], 0, 0, 0);
      }
      __builtin_amdgcn_s_setprio(0);
    }

    // epilogue: concat[b][qrow][h*64 + d], d = 16mf + 4lg + r
    const float inv = 1.f / lrun;
#pragma unroll
    for (int mf = 0; mf < 4; ++mf) {
      uint2 ov;
      ov.x = pk2bf(o[mf][0] * inv, o[mf][1] * inv);
      ov.y = pk2bf(o[mf][2] * inv, o[mf][3] * inv);
      *(uint2*)(concat + (size_t)(b * L_SEQ + qrow) * D_MODEL + h * HKD +
                mf * 16 + lg * 4) = ov;
    }
  }
}

// ---------------------------------------------------------------------------
extern "C" void kernel_launch(void* const* d_in, const int* in_sizes, int n_in,
                              void* d_out, int out_size, void* d_ws, size_t ws_size,
                              hipStream_t stream) {
  const float* x    = (const float*)d_in[0];  // (2, 2048, 1024)
  const float* wqkv = (const float*)d_in[1];  // (1024, 3072)
  const float* wend = (const float*)d_in[2];  // (1024, 1024)
  float* out = (float*)d_out;                 // (2, 2048, 1024) fp32

  char* ws = (char*)d_ws;
  unsigned short* qkv   = (unsigned short*)(ws);              // 24 MB bf16
  unsigned short* xb    = (unsigned short*)(ws + 25165824);   //  8 MB (dead after GEMM1 -> vT)
  unsigned short* wqkvT = (unsigned short*)(ws + 33554432);   //  6 MB [3072][1024]
  unsigned short* wendT = (unsigned short*)(ws + 39845888);   //  2 MB [1024][1024]
  unsigned short* cat   = (unsigned short*)(ws + 41943040);   //  8 MB
  unsigned short* vT    = xb;                                 //  8 MB [32][64][2048]

  cvt_f32_bf16<<<2048, 256, 0, stream>>>(x, xb);
  transpose_cvt<<<dim3(48, 16), 256, 0, stream>>>(wqkv, wqkvT, 1024, 3072);
  transpose_cvt<<<dim3(16, 16), 256, 0, stream>>>(wend, wendT, 1024, 1024);

  // qkv = x @ wqkv   (M=4096, N=3072, K=1024) -> bf16
  gemm_bf16<unsigned short><<<dim3(24, 32), 256, 0, stream>>>(
      xb, wqkvT, qkv, 4096, 3072, 1024);
  // V^T pre-transpose (xb dead; vT aliases it)
  transpose_v<<<dim3(32, 32), 256, 0, stream>>>(qkv, vT);
  // flash attention -> concat bf16 (256 uniform-work blocks)
  attn_mfma<<<256, 512, 0, stream>>>(qkv, vT, cat);
  // out = concat @ wend  (M=4096, N=1024, K=1024) -> fp32
  gemm_bf16<float><<<dim3(8, 32), 256, 0, stream>>>(
      cat, wendT, out, 4096, 1024, 1024);
}

// Round 10
// 194.344 us; speedup vs baseline: 1.2787x; 1.0931x over previous
//
#include <hip/hip_runtime.h>
#include <hip/hip_bf16.h>
#include <cstddef>
#include <cstdint>

// (B, L, D, H) = (2, 2048, 1024, 16), KD = 64.
#define L_SEQ   2048
#define D_MODEL 1024
#define NH      16
#define HKD     64
#define TD3     3072
#define NBATCH  2

typedef __attribute__((ext_vector_type(8))) short bf16x8;
typedef __attribute__((ext_vector_type(4))) float f32x4;

__device__ __forceinline__ unsigned short f2bf(float f) {
  unsigned int u = __float_as_uint(f);
  u += 0x7fffu + ((u >> 16) & 1u);   // round-to-nearest-even
  return (unsigned short)(u >> 16);
}

__device__ __forceinline__ unsigned int pk2bf(float a, float b) {
  union { __hip_bfloat162 h; unsigned int u; } cv;
  cv.h = __float22bfloat162_rn(make_float2(a, b));
  return cv.u;
}

__device__ __forceinline__ void gll16(const void* g, void* l) {
  __builtin_amdgcn_global_load_lds(
      (const __attribute__((address_space(1))) unsigned int*)g,
      (__attribute__((address_space(3))) unsigned int*)l, 16, 0, 0);
}

// ---------------------------------------------------------------------------
// fp32 -> bf16, 8 elems/thread
// ---------------------------------------------------------------------------
__global__ __launch_bounds__(256)
void cvt_f32_bf16(const float* __restrict__ in, unsigned short* __restrict__ out) {
  const int i = blockIdx.x * 256 + threadIdx.x;
  const float4 a = ((const float4*)in)[2 * i];
  const float4 b = ((const float4*)in)[2 * i + 1];
  bf16x8 v;
  v[0] = (short)f2bf(a.x); v[1] = (short)f2bf(a.y);
  v[2] = (short)f2bf(a.z); v[3] = (short)f2bf(a.w);
  v[4] = (short)f2bf(b.x); v[5] = (short)f2bf(b.y);
  v[6] = (short)f2bf(b.z); v[7] = (short)f2bf(b.w);
  ((bf16x8*)out)[i] = v;
}

// ---------------------------------------------------------------------------
// W[K][N] fp32 -> WT[N][K] bf16 (64x64 tiles through LDS)
// ---------------------------------------------------------------------------
__global__ __launch_bounds__(256)
void transpose_cvt(const float* __restrict__ W, unsigned short* __restrict__ WT,
                   int K, int N) {
  __shared__ unsigned short T[64][68];
  const int t = threadIdx.x;
  const int n0 = blockIdx.x * 64, k0 = blockIdx.y * 64;
  const int cr = t >> 4, cc = (t & 15) * 4;
#pragma unroll
  for (int i = 0; i < 4; ++i) {
    const int k = cr + 16 * i;
    const float4 v = *(const float4*)(W + (size_t)(k0 + k) * N + n0 + cc);
    T[cc + 0][k] = f2bf(v.x); T[cc + 1][k] = f2bf(v.y);
    T[cc + 2][k] = f2bf(v.z); T[cc + 3][k] = f2bf(v.w);
  }
  __syncthreads();
#pragma unroll
  for (int i = 0; i < 4; ++i) {
    const int n = cr + 16 * i;
    ushort4 o;
    o.x = T[n][cc]; o.y = T[n][cc + 1]; o.z = T[n][cc + 2]; o.w = T[n][cc + 3];
    *(ushort4*)(WT + (size_t)(n0 + n) * K + k0 + cc) = o;
  }
}

// ---------------------------------------------------------------------------
// bf16 MFMA GEMM: C[M,N] = A[M,K] * Bt[N,K]^T.
// 128x128 tile, BK=64, 256 threads (4 waves, 2x2), 4x4 16x16x32 frags/wave.
// DOUBLE-BUFFERED LDS (one barrier per k-step; prefetch hides under compute)
// + chunk-XOR swizzled staging (kills the 128B-row 16-way bank conflict).
// XCD-aware block swizzle (grid multiple of 8).
// ---------------------------------------------------------------------------
template <typename OUT>
__device__ __forceinline__ OUT cvt_out(float f);
template <> __device__ __forceinline__ float cvt_out<float>(float f) { return f; }
template <> __device__ __forceinline__ unsigned short cvt_out<unsigned short>(float f) { return f2bf(f); }

template <typename OUT>
__global__ __launch_bounds__(256)
void gemm_bf16(const unsigned short* __restrict__ A,   // [M][K] bf16
               const unsigned short* __restrict__ Bt,  // [N][K] bf16
               OUT* __restrict__ C, int M, int N, int K) {
  __shared__ unsigned short As[2][128 * 64];   // 2 x 16 KB
  __shared__ unsigned short Bs[2][128 * 64];   // 2 x 16 KB
  const int t = threadIdx.x, w = t >> 6, lane = t & 63;
  const int lg = lane >> 4, lq = lane & 15;

  // XCD swizzle: contiguous chunk of blocks per XCD (nwg % 8 == 0)
  const int nwg = gridDim.x * gridDim.y;
  int bid = blockIdx.y * gridDim.x + blockIdx.x;
  bid = (bid & 7) * (nwg >> 3) + (bid >> 3);
  const int m0 = (bid / gridDim.x) * 128, n0 = (bid % gridDim.x) * 128;
  const int wr = w >> 1, wc = w & 1;

  // staging: thread t stages 16B chunks c = 256*i + t (i=0..3) of each tile.
  // LDS dest linear; SOURCE column chunk XOR-swizzled (involution; frag
  // reads apply the same XOR -> conflict-free 2-way reads).
  const int srow = t >> 3;                      // 0..31 (+32 per i)
  const int ssw = ((t & 7) ^ (srow & 7)) * 8;   // source col offset (elems)
  const size_t aSrc = (size_t)(m0 + srow) * K + ssw;
  const size_t bSrc = (size_t)(n0 + srow) * K + ssw;

  auto STAGE = [&](int buf, int k0) {
#pragma unroll
    for (int i = 0; i < 4; ++i) {
      gll16(A + aSrc + (size_t)(32 * i) * K + k0,
            (char*)&As[buf][0] + (256 * i + 64 * w) * 16);
      gll16(Bt + bSrc + (size_t)(32 * i) * K + k0,
            (char*)&Bs[buf][0] + (256 * i + 64 * w) * 16);
    }
  };

  f32x4 acc[4][4];
#pragma unroll
  for (int a = 0; a < 4; ++a)
#pragma unroll
    for (int b = 0; b < 4; ++b) acc[a][b] = (f32x4)0.f;

  // prologue: stage tile 0 into buffer 0
  STAGE(0, 0);

  const int KT = K >> 6;
  for (int kt = 0; kt < KT; ++kt) {
    const int cur = kt & 1;
    __syncthreads();   // drains vmcnt: buf[cur] ready; prev reads of buf[cur^1] done

    if (kt + 1 < KT) STAGE(cur ^ 1, (kt + 1) << 6);  // prefetch overlaps compute

    const char* ab = (const char*)&As[cur][0];
    const char* bb = (const char*)&Bs[cur][0];
#pragma unroll
    for (int ks = 0; ks < 2; ++ks) {
      bf16x8 af[4], bfr[4];
#pragma unroll
      for (int mf = 0; mf < 4; ++mf) {
        const int row = wr * 64 + mf * 16 + lq;
        af[mf] = *(const bf16x8*)(ab + row * 128 +
                                  (((ks << 2) + lg) ^ (lq & 7)) * 16);
      }
#pragma unroll
      for (int nf = 0; nf < 4; ++nf) {
        const int row = wc * 64 + nf * 16 + lq;
        bfr[nf] = *(const bf16x8*)(bb + row * 128 +
                                   (((ks << 2) + lg) ^ (lq & 7)) * 16);
      }
#pragma unroll
      for (int mf = 0; mf < 4; ++mf)
#pragma unroll
        for (int nf = 0; nf < 4; ++nf)
          acc[mf][nf] = __builtin_amdgcn_mfma_f32_16x16x32_bf16(
              af[mf], bfr[nf], acc[mf][nf], 0, 0, 0);
    }
  }

  // C/D layout: col = lane&15, row = (lane>>4)*4 + reg  [m89]
#pragma unroll
  for (int mf = 0; mf < 4; ++mf)
#pragma unroll
    for (int nf = 0; nf < 4; ++nf) {
      const int col = n0 + wc * 64 + nf * 16 + lq;
#pragma unroll
      for (int r = 0; r < 4; ++r) {
        const int row = m0 + wr * 64 + mf * 16 + lg * 4 + r;
        C[(size_t)row * N + col] = cvt_out<OUT>(acc[mf][nf][r]);
      }
    }
}

// ---------------------------------------------------------------------------
// Reference's direct reshape: head h, attn row s <-> memory row h*128 + s/16,
// cols (s%16)*64 (+ part*D_MODEL).
// ---------------------------------------------------------------------------
__device__ __forceinline__ size_t head_row(int part, int b, int h, int s) {
  return ((size_t)(b * L_SEQ + h * 128 + (s >> 4))) * TD3 +
         (size_t)part * D_MODEL + (size_t)(s & 15) * HKD;
}

// ---------------------------------------------------------------------------
// V pre-transpose: vT[b][h][d][s]
// ---------------------------------------------------------------------------
__global__ __launch_bounds__(256)
void transpose_v(const unsigned short* __restrict__ qkv,
                 unsigned short* __restrict__ vT) {
  __shared__ unsigned short T[64][68];
  const int t = threadIdx.x;
  const int kt = blockIdx.x, bh = blockIdx.y, b = bh >> 4, h = bh & 15;
  const int s0 = kt * 64;
  const int sr = t >> 4, c4 = (t & 15) * 4;
#pragma unroll
  for (int i = 0; i < 4; ++i) {
    const int s = sr + 16 * i;
    const ushort4 v = *(const ushort4*)(qkv + head_row(2, b, h, s0 + s) + c4);
    T[c4 + 0][s] = v.x; T[c4 + 1][s] = v.y;
    T[c4 + 2][s] = v.z; T[c4 + 3][s] = v.w;
  }
  __syncthreads();
#pragma unroll
  for (int i = 0; i < 4; ++i) {
    const int d = sr + 16 * i;
    ushort4 o;
    o.x = T[d][c4]; o.y = T[d][c4 + 1]; o.z = T[d][c4 + 2]; o.w = T[d][c4 + 3];
    *(ushort4*)(vT + ((size_t)(bh * 64 + d)) * L_SEQ + s0 + c4) = o;
  }
}

// ---------------------------------------------------------------------------
// MFMA flash attention. Each block processes TWO q-blocks sequentially:
// qt_hi = 15-p then qt_lo = p  ->  every block = exactly 34 K/V tiles
// (perfect load balance, scheduler-independent). 8 waves, QBLK=128/pass,
// KVBLK=64, dbuf K/V^T via global_load_lds. Swapped operands:
// S^T = mfma(K, Q^T), O^T = mfma(V^T, P^T). Log2-domain softmax, wave-uniform
// diag masking, defer-max, masked-wave skip, bh->XCD clustered launch.
// ---------------------------------------------------------------------------
#define QK_SCALE 0.18033688011112043f   // log2(e)/8

__global__ __launch_bounds__(512)
void attn_mfma(const unsigned short* __restrict__ qkv,
               const unsigned short* __restrict__ vT,
               unsigned short* __restrict__ concat) {
  __shared__ unsigned short Ks[2][64 * 64];  // [key][d], chunk-XOR swizzled
  __shared__ unsigned short Vs[2][64 * 64];  // [d][key], chunk-XOR swizzled
  __shared__ unsigned short Pl[8][16][72];   // per-wave P[q][key], padded

  const int t = threadIdx.x, w = t >> 6, lane = t & 63;
  const int lg = lane >> 4, lq = lane & 15;

  // 256 blocks: xcd = bid&7 (round-robin XCD), per XCD 4 bh x 8 pairs.
  const int bid = blockIdx.x;
  const int xcd = bid & 7, idx = bid >> 3;       // idx 0..31
  const int bh = xcd + 8 * (idx & 3);
  const int pair = idx >> 2;                     // 0..7
  const int b = bh >> 4, h = bh & 15;

  // staging: thread t stages 16B chunk t of each 64x64 tile.
  // dest linear; source column XOR-swizzled (involution; reads apply same).
  const int srow = t >> 3;                       // 0..63
  const int swz = ((t & 7) ^ (srow & 7)) * 8;
  const size_t kSrc = head_row(1, b, h, srow) + swz;            // += k0*192
  const size_t vSrc = ((size_t)(bh * 64 + srow)) * L_SEQ + swz; // += k0
  char* const kDst = (char*)&Ks[0][0] + w * 1024;
  char* const vDst = (char*)&Vs[0][0] + w * 1024;

  for (int pass = 0; pass < 2; ++pass) {
    const int qt = pass ? pair : 15 - pair;      // qt_hi + qt_lo = 15
    const int q0 = qt * 128;
    const int qrow = q0 + w * 16 + lq;           // this lane's q row

    // Q fragments, pre-scaled by log2(e)/sqrt(KD) (softmax in log2 domain)
    bf16x8 qf[2];
    {
      const size_t qb = head_row(0, b, h, qrow) + lg * 8;
      qf[0] = *(const bf16x8*)(qkv + qb);
      qf[1] = *(const bf16x8*)(qkv + qb + 32);
#pragma unroll
      for (int s = 0; s < 2; ++s)
#pragma unroll
        for (int j = 0; j < 8; ++j) {
          const float f =
              __uint_as_float(((unsigned int)(unsigned short)qf[s][j]) << 16);
          qf[s][j] = (short)f2bf(f * QK_SCALE);
        }
    }

    f32x4 o[4];
#pragma unroll
    for (int mf = 0; mf < 4; ++mf) o[mf] = (f32x4)0.f;
    float mrun = -1e30f, lrun = 0.f;

    const int ktmax = 2 * qt + 1;

    __syncthreads();  // previous pass's LDS reads done before re-staging buf0
    // prologue: stage tile 0 into buffer 0
    gll16(qkv + kSrc, kDst);
    gll16(vT + vSrc, vDst);

    for (int kt = 0; kt <= ktmax; ++kt) {
      const int k0 = kt * 64;
      const int cur = kt & 1;
      __syncthreads();  // vmcnt drained: buf[cur] ready; buf[1-cur] reads done

      if (kt < ktmax) {  // prefetch next tile into other buffer
        gll16(qkv + kSrc + (size_t)(k0 + 64) * 192, kDst + (1 - cur) * 8192);
        gll16(vT + vSrc + (size_t)(k0 + 64), vDst + (1 - cur) * 8192);
      }

      // waves whose q-strip lies entirely above this K-tile skip all compute
      if (k0 > q0 + w * 16 + 15) continue;

      const char* kb = (const char*)&Ks[cur][0];
      const char* vb = (const char*)&Vs[cur][0];

      // S^T = K * Q^T : lane holds S^T[key=16mf+4lg+r][q=lq] (log2-scaled)
      f32x4 s[4];
#pragma unroll
      for (int mf = 0; mf < 4; ++mf) s[mf] = (f32x4)0.f;
      __builtin_amdgcn_s_setprio(1);
#pragma unroll
      for (int ks = 0; ks < 2; ++ks) {
        bf16x8 kf[4];
#pragma unroll
        for (int mf = 0; mf < 4; ++mf) {
          const int key = mf * 16 + lq;
          const int chunk = (lg + 4 * ks) ^ (key & 7);
          kf[mf] = *(const bf16x8*)(kb + key * 128 + chunk * 16);
        }
#pragma unroll
        for (int mf = 0; mf < 4; ++mf)
          s[mf] = __builtin_amdgcn_mfma_f32_16x16x32_bf16(kf[mf], qf[ks], s[mf], 0, 0, 0);
      }
      __builtin_amdgcn_s_setprio(0);

      // online softmax, log2 domain.
      // Mask needed iff tile max key (k0+63) exceeds wave MIN q-row (qrow-lq).
      float sv[16];
      if (k0 + 63 > qrow - lq) {                 // wave-uniform
#pragma unroll
        for (int mf = 0; mf < 4; ++mf)
#pragma unroll
          for (int r = 0; r < 4; ++r) {
            float x = s[mf][r];
            if (k0 + mf * 16 + lg * 4 + r > qrow) x = -1e30f;
            sv[mf * 4 + r] = x;
          }
      } else {
#pragma unroll
        for (int mf = 0; mf < 4; ++mf)
#pragma unroll
          for (int r = 0; r < 4; ++r) sv[mf * 4 + r] = s[mf][r];
      }
      float t0 = fmaxf(fmaxf(sv[0], sv[1]), fmaxf(sv[2], sv[3]));
      float t1 = fmaxf(fmaxf(sv[4], sv[5]), fmaxf(sv[6], sv[7]));
      float t2 = fmaxf(fmaxf(sv[8], sv[9]), fmaxf(sv[10], sv[11]));
      float t3 = fmaxf(fmaxf(sv[12], sv[13]), fmaxf(sv[14], sv[15]));
      float tmax = fmaxf(fmaxf(t0, t1), fmaxf(t2, t3));
      tmax = fmaxf(tmax, __shfl_xor(tmax, 16));
      tmax = fmaxf(tmax, __shfl_xor(tmax, 32));

      if (!__all(tmax - mrun <= 8.f)) {          // defer-max: rescale rarely
        const float mnew = fmaxf(mrun, tmax);
        const float sc = __builtin_amdgcn_exp2f(mrun - mnew);
        lrun *= sc;
#pragma unroll
        for (int mf = 0; mf < 4; ++mf) {
          o[mf][0] *= sc; o[mf][1] *= sc; o[mf][2] *= sc; o[mf][3] *= sc;
        }
        mrun = mnew;
      }

      float rs = 0.f;
#pragma unroll
      for (int mf = 0; mf < 4; ++mf) {
        const float p0 = __builtin_amdgcn_exp2f(sv[mf * 4 + 0] - mrun);
        const float p1 = __builtin_amdgcn_exp2f(sv[mf * 4 + 1] - mrun);
        const float p2 = __builtin_amdgcn_exp2f(sv[mf * 4 + 2] - mrun);
        const float p3 = __builtin_amdgcn_exp2f(sv[mf * 4 + 3] - mrun);
        rs += (p0 + p1) + (p2 + p3);
        uint2 pk;
        pk.x = pk2bf(p0, p1);
        pk.y = pk2bf(p2, p3);
        *(uint2*)&Pl[w][lq][mf * 16 + lg * 4] = pk;
      }
      rs += __shfl_xor(rs, 16);
      rs += __shfl_xor(rs, 32);
      lrun += rs;

      // O^T += V^T * P^T   (per-wave Pl strip: same-wave write->read)
      __builtin_amdgcn_s_setprio(1);
#pragma unroll
      for (int ks = 0; ks < 2; ++ks) {
        const bf16x8 pf = *(const bf16x8*)&Pl[w][lq][ks * 32 + lg * 8];
        bf16x8 vf[4];
#pragma unroll
        for (int mf = 0; mf < 4; ++mf) {
          const int d = mf * 16 + lq;
          const int chunk = (lg + 4 * ks) ^ (d & 7);
          vf[mf] = *(const bf16x8*)(vb + d * 128 + chunk * 16);
        }
#pragma unroll
        for (int mf = 0; mf < 4; ++mf)
          o[mf] = __builtin_amdgcn_mfma_f32_16x16x32_bf16(vf[mf], pf, o[mf], 0, 0, 0);
      }
      __builtin_amdgcn_s_setprio(0);
    }

    // epilogue: concat[b][qrow][h*64 + d], d = 16mf + 4lg + r
    const float inv = 1.f / lrun;
#pragma unroll
    for (int mf = 0; mf < 4; ++mf) {
      uint2 ov;
      ov.x = pk2bf(o[mf][0] * inv, o[mf][1] * inv);
      ov.y = pk2bf(o[mf][2] * inv, o[mf][3] * inv);
      *(uint2*)(concat + (size_t)(b * L_SEQ + qrow) * D_MODEL + h * HKD +
                mf * 16 + lg * 4) = ov;
    }
  }
}

// ---------------------------------------------------------------------------
extern "C" void kernel_launch(void* const* d_in, const int* in_sizes, int n_in,
                              void* d_out, int out_size, void* d_ws, size_t ws_size,
                              hipStream_t stream) {
  const float* x    = (const float*)d_in[0];  // (2, 2048, 1024)
  const float* wqkv = (const float*)d_in[1];  // (1024, 3072)
  const float* wend = (const float*)d_in[2];  // (1024, 1024)
  float* out = (float*)d_out;                 // (2, 2048, 1024) fp32

  char* ws = (char*)d_ws;
  unsigned short* qkv   = (unsigned short*)(ws);              // 24 MB bf16
  unsigned short* xb    = (unsigned short*)(ws + 25165824);   //  8 MB (dead after GEMM1 -> vT)
  unsigned short* wqkvT = (unsigned short*)(ws + 33554432);   //  6 MB [3072][1024]
  unsigned short* wendT = (unsigned short*)(ws + 39845888);   //  2 MB [1024][1024]
  unsigned short* cat   = (unsigned short*)(ws + 41943040);   //  8 MB
  unsigned short* vT    = xb;                                 //  8 MB [32][64][2048]

  cvt_f32_bf16<<<2048, 256, 0, stream>>>(x, xb);
  transpose_cvt<<<dim3(48, 16), 256, 0, stream>>>(wqkv, wqkvT, 1024, 3072);
  transpose_cvt<<<dim3(16, 16), 256, 0, stream>>>(wend, wendT, 1024, 1024);

  // qkv = x @ wqkv   (M=4096, N=3072, K=1024) -> bf16
  gemm_bf16<unsigned short><<<dim3(24, 32), 256, 0, stream>>>(
      xb, wqkvT, qkv, 4096, 3072, 1024);
  // V^T pre-transpose (xb dead; vT aliases it)
  transpose_v<<<dim3(32, 32), 256, 0, stream>>>(qkv, vT);
  // flash attention -> concat bf16 (256 uniform-work blocks)
  attn_mfma<<<256, 512, 0, stream>>>(qkv, vT, cat);
  // out = concat @ wend  (M=4096, N=1024, K=1024) -> fp32
  gemm_bf16<float><<<dim3(8, 32), 256, 0, stream>>>(
      cat, wendT, out, 4096, 1024, 1024);
}